// Round 5
// baseline (220.482 us; speedup 1.0000x reference)
//
#include <hip/hip_runtime.h>

#define F 64
#define NCH 256          // edge chunks (= blocks) for hist/scatter passes
// buckets are 256 nodes wide: bucket = dst >> 8. N=100000 -> NB=391
// packing: ebuf entry = src | (dst&255)<<17  (needs N < 131072)

typedef __attribute__((ext_vector_type(8))) short bf16x8;
typedef __attribute__((ext_vector_type(4))) float f32x4;

static __device__ __forceinline__ unsigned short f2bf(float f) {
    unsigned u = __float_as_uint(f);
    return (unsigned short)((u + 0x7fffu + ((u >> 16) & 1u)) >> 16);   // RNE
}
static __device__ __forceinline__ float bflo(unsigned u) { return __uint_as_float(u << 16); }
static __device__ __forceinline__ float bfhi(unsigned u) { return __uint_as_float(u & 0xffff0000u); }

// ---- launch 1: chunk bucket hist + W1t/W2t prep + zero(deg) ----
// blocks [0,NCH): per-chunk bucket histogram
// block NCH / NCH+1: W1 / W2 -> bf16 transposed
// blocks [NCH+2, NCH+2+gZ): deg[] = 0 (atomics target for launch 2)
__global__ __launch_bounds__(256) void k_fused0(const int* __restrict__ dst,
                                                int* __restrict__ histM,
                                                const float* __restrict__ W1,
                                                const float* __restrict__ W2,
                                                unsigned short* __restrict__ W1t,
                                                unsigned short* __restrict__ W2t,
                                                int* __restrict__ deg,
                                                int E, int chunk, int NB, int N) {
    __shared__ int h[512];                   // NB <= 512
    const int t = threadIdx.x;
    const int b = blockIdx.x;
    if (b >= NCH + 2) {                      // ---- zero-deg role ----
        int base = (b - NCH - 2) * 1024 + t * 4;
        if (base + 3 < N) {
            *(int4*)&deg[base] = make_int4(0, 0, 0, 0);
        } else {
            for (int j = 0; j < 4; ++j) if (base + j < N) deg[base + j] = 0;
        }
        return;
    }
    if (b >= NCH) {                          // ---- weight prep role ----
        int which = b - NCH;
        const float* W = which ? W2 : W1;
        unsigned short* Wt = which ? W2t : W1t;
#pragma unroll
        for (int i = 0; i < 16; ++i) {
            int e = t + i * 256;
            int n = e >> 6, k = e & 63;
            Wt[e] = f2bf(W[k * 64 + n]);
        }
        return;
    }
    // ---- histogram role ----
    for (int i = t; i < NB; i += 256) h[i] = 0;
    __syncthreads();
    const int lo = b * chunk;
    const int hi = min(E, lo + chunk);
    for (int e = lo + t; e < hi; e += 256) {
        atomicAdd(&h[dst[e] >> 8], 1);
    }
    __syncthreads();
    for (int i = t; i < NB; i += 256) histM[i * NCH + b] = h[i];
}

// ---- launch 2: s_part partials + global degree count ----
// blocks [0,nb): per-1024 partial sums of histM
// blocks [nb, nb+NCH): deg[dst[e]]++ (fire-and-forget global atomics; dst L2-hot)
__global__ __launch_bounds__(256) void k_partdeg(const int* __restrict__ v,
                                                 int* __restrict__ part,
                                                 const int* __restrict__ dst,
                                                 int* __restrict__ deg,
                                                 int M, int E, int chunk, int nb) {
    __shared__ int sd[256];
    const int t = threadIdx.x;
    const int b = blockIdx.x;
    if (b >= nb) {                           // ---- degree-count role ----
        const int c = b - nb;
        const int lo = c * chunk;
        const int hi = min(E, lo + chunk);
        for (int e = lo + t; e < hi; e += 256)
            atomicAdd(&deg[dst[e]], 1);
        return;
    }
    const int base = b * 1024 + t * 4;
    int s = 0;
    if (base + 3 < M) {
        int4 d = *(const int4*)&v[base];
        s = d.x + d.y + d.z + d.w;
    } else {
#pragma unroll
        for (int j = 0; j < 4; ++j) if (base + j < M) s += v[base + j];
    }
    sd[t] = s;
    __syncthreads();
    for (int off = 128; off > 0; off >>= 1) {
        if (t < off) sd[t] += sd[t + off];
        __syncthreads();
    }
    if (t == 0) part[b] = sd[0];
}

// ---- launch 3: scan-emit (inline prefix of raw partials) + deg -> dinv ----
// blocks [0,nb): emit scanned histM (each block sums part[0..b) itself; nb<=256)
// blocks [nb, nb+gD): dinv[n] = rsqrt(deg[n]+1)
__global__ __launch_bounds__(256) void k_emitdinv(int* __restrict__ v,
                                                  const int* __restrict__ part,
                                                  const int* __restrict__ deg,
                                                  float* __restrict__ dinv,
                                                  int M, int N, int nb) {
    __shared__ int sums[256];
    __shared__ int red[256];
    const int t = threadIdx.x;
    const int b = blockIdx.x;
    if (b >= nb) {                           // ---- dinv role ----
        int base = (b - nb) * 1024 + t * 4;
        if (base + 3 < N) {
            int4 d = *(const int4*)&deg[base];
            float4 o = make_float4(rsqrtf((float)(d.x + 1)), rsqrtf((float)(d.y + 1)),
                                   rsqrtf((float)(d.z + 1)), rsqrtf((float)(d.w + 1)));
            *(float4*)&dinv[base] = o;
        } else {
            for (int j = 0; j < 4; ++j)
                if (base + j < N) dinv[base + j] = rsqrtf((float)(deg[base + j] + 1));
        }
        return;
    }
    // exclusive prefix of raw partials for this block (nb <= 256)
    red[t] = (t < b) ? part[t] : 0;
    __syncthreads();
    for (int off = 128; off > 0; off >>= 1) {
        if (t < off) red[t] += red[t + off];
        __syncthreads();
    }
    const int pref = red[0];

    const int base = b * 1024 + t * 4;
    int d0 = 0, d1 = 0, d2 = 0, d3 = 0;
    if (base + 3 < M) {
        int4 d = *(const int4*)&v[base];
        d0 = d.x; d1 = d.y; d2 = d.z; d3 = d.w;
    } else {
        if (base + 0 < M) d0 = v[base + 0];
        if (base + 1 < M) d1 = v[base + 1];
        if (base + 2 < M) d2 = v[base + 2];
        if (base + 3 < M) d3 = v[base + 3];
    }
    int tot = d0 + d1 + d2 + d3;
    sums[t] = tot;
    __syncthreads();
    for (int off = 1; off < 256; off <<= 1) {
        int x = (t >= off) ? sums[t - off] : 0;
        __syncthreads();
        sums[t] += x;
        __syncthreads();
    }
    int o0 = pref + sums[t] - tot;
    int e0 = o0, e1 = o0 + d0, e2 = e1 + d1, e3 = e2 + d2;
    if (base + 3 < M) {
        *(int4*)&v[base] = make_int4(e0, e1, e2, e3);
    } else {
        int ee[4] = {e0, e1, e2, e3};
        for (int j = 0; j < 4; ++j) if (base + j < M) v[base + j] = ee[j];
    }
}

// ---- launch 4: scatter packed edges (blocks [0,NCH)) || gemm1 (rest) ----
// scatter is atomic/latency-bound, gemm1 is MFMA/BW-bound: complementary roles
// overlap instead of running as two serial launches. gemm1 needs dinv (launch 3).
__global__ __launch_bounds__(256) void k_scatgemm(const int* __restrict__ src,
                                                  const int* __restrict__ dst,
                                                  const int* __restrict__ scanM,
                                                  int* __restrict__ ebuf,
                                                  const float* __restrict__ X,
                                                  const unsigned short* __restrict__ W1t,
                                                  const float* __restrict__ dinv,
                                                  unsigned short* __restrict__ hs1,
                                                  int E, int chunk, int NB, int N) {
    __shared__ unsigned short SMa[64 * 72];   // gemm Wl | scatter cur (aliased)
    __shared__ unsigned short SMb[64 * 72];   // gemm Xs
    const int t = threadIdx.x;
    const int b = blockIdx.x;

    if (b < NCH) {                            // ---- scatter role ----
        int* cur = (int*)SMa;                 // needs NB<=512 ints = 2KB <= 9.2KB
        for (int i = t; i < NB; i += 256) cur[i] = scanM[i * NCH + b];
        __syncthreads();
        const int lo = b * chunk;
        const int hi = min(E, lo + chunk);
        for (int e = lo + t; e < hi; e += 256) {
            int s = src[e];
            int d = dst[e];
            int p = atomicAdd(&cur[d >> 8], 1);
            ebuf[p] = s | ((d & 255) << 17);
        }
        return;
    }

    // ---- gemm1 role: hs1 rows = (X @ W1) * dinv[row], bf16 ----
    unsigned short* Wl = SMa;
    unsigned short* Xs = SMb;
    const int row0 = (b - NCH) * 64;
#pragma unroll
    for (int i = 0; i < 2; ++i) {
        int idx = t + i * 256;
        int n = idx >> 3, k = (idx & 7) * 8;
        *(uint4*)&Wl[n * 72 + k] = ((const uint4*)W1t)[idx];
    }
#pragma unroll
    for (int i = 0; i < 4; ++i) {
        int idx = t + i * 256;
        int r = idx >> 4, c = (idx & 15) * 4;
        int gr = row0 + r;
        float4 v = make_float4(0.f, 0.f, 0.f, 0.f);
        if (gr < N) v = *(const float4*)&X[(size_t)gr * F + c];
        unsigned p0 = (unsigned)f2bf(v.x) | ((unsigned)f2bf(v.y) << 16);
        unsigned p1 = (unsigned)f2bf(v.z) | ((unsigned)f2bf(v.w) << 16);
        *(uint2*)&Xs[r * 72 + c] = make_uint2(p0, p1);
    }
    __syncthreads();

    const int w    = t >> 6;
    const int lane = t & 63;
    const int l15  = lane & 15;
    const int quad = lane >> 4;

    bf16x8 bf[4][2];
#pragma unroll
    for (int ct = 0; ct < 4; ++ct)
#pragma unroll
        for (int kc = 0; kc < 2; ++kc)
            bf[ct][kc] = *(const bf16x8*)&Wl[(ct * 16 + l15) * 72 + kc * 32 + quad * 8];

    const int am = w * 16 + l15;
    bf16x8 af0 = *(const bf16x8*)&Xs[am * 72 + quad * 8];
    bf16x8 af1 = *(const bf16x8*)&Xs[am * 72 + 32 + quad * 8];

    f32x4 acc[4];
#pragma unroll
    for (int ct = 0; ct < 4; ++ct) {
        f32x4 z = {0.f, 0.f, 0.f, 0.f};
        z = __builtin_amdgcn_mfma_f32_16x16x32_bf16(af0, bf[ct][0], z, 0, 0, 0);
        z = __builtin_amdgcn_mfma_f32_16x16x32_bf16(af1, bf[ct][1], z, 0, 0, 0);
        acc[ct] = z;
    }

    float dv[4];
#pragma unroll
    for (int r = 0; r < 4; ++r) {
        int row = row0 + w * 16 + quad * 4 + r;
        dv[r] = (row < N) ? dinv[row] : 0.f;
    }
#pragma unroll
    for (int ct = 0; ct < 4; ++ct) {
#pragma unroll
        for (int r = 0; r < 4; ++r) {
            int row = row0 + w * 16 + quad * 4 + r;
            if (row < N)
                hs1[(size_t)row * F + ct * 16 + l15] = f2bf(acc[ct][r] * dv[r]);
        }
    }
}

// ---- launch 5: per-bucket LDS counting sort -> rowptr, node-sorted csr ----
// (dinv now produced by the deg path; dropped here)
__global__ __launch_bounds__(256) void k_csr(const int* __restrict__ ebuf,
                                             const int* __restrict__ scanM,
                                             int* __restrict__ rowptr,
                                             int* __restrict__ csr,
                                             int N, int E, int NB) {
    __shared__ int hist[256];
    __shared__ int scn[256];
    __shared__ int cur[256];
    const int t = threadIdx.x;
    const int bkt = blockIdx.x;
    const int beg = scanM[bkt * NCH];
    const int end = (bkt + 1 < NB) ? scanM[(bkt + 1) * NCH] : E;

    hist[t] = 0;
    __syncthreads();
    for (int e = beg + t; e < end; e += 256)
        atomicAdd(&hist[((unsigned)ebuf[e]) >> 17], 1);
    __syncthreads();

    scn[t] = hist[t];
    __syncthreads();
    for (int off = 1; off < 256; off <<= 1) {
        int v = (t >= off) ? scn[t - off] : 0;
        __syncthreads();
        scn[t] += v;
        __syncthreads();
    }

    {
        int excl = scn[t] - hist[t];
        int rp = beg + excl;
        int node = (bkt << 8) + t;
        cur[t] = rp;
        if (node < N) rowptr[node] = rp;
    }
    if (bkt == NB - 1 && t == 0) rowptr[N] = E;
    __syncthreads();

    for (int e = beg + t; e < end; e += 256) {
        int pk = ebuf[e];
        int p = atomicAdd(&cur[((unsigned)pk) >> 17], 1);
        csr[p] = pk & 0x1FFFF;
    }
}

// ---- launch 6: fused agg1 + gemm2 (R1 best-measured variant, 256-node buckets) ----
// hs2 emitted in SLICED layout: hs2[(slice*N + node)*16 + pos], slice=feature>>4.
__global__ __launch_bounds__(512) void k_aggmm(const unsigned short* __restrict__ hs1,
                                               const int* __restrict__ rowptr,
                                               const int* __restrict__ csr,
                                               const unsigned short* __restrict__ W2t,
                                               const float* __restrict__ b1,
                                               unsigned short* __restrict__ hs2, int N) {
    __shared__ unsigned short Act[256 * 72];   // act1 bf16, stride 72
    __shared__ unsigned short Wl[64 * 72];     // W2t padded
    __shared__ float sdv[256];                 // per-node dinv
    const int t = threadIdx.x;
    const int node0 = blockIdx.x << 8;

    {
        int idx = t;                           // 512 uint4 = full 4096 bf16
        int n = idx >> 3, k = (idx & 7) * 8;
        *(uint4*)&Wl[n * 72 + k] = ((const uint4*)W2t)[idx];
    }

    const int lane = t & 7;
    const int nsub = t >> 3;                   // 0..63
    const uint4* hsb = (const uint4*)hs1;
    float4 bb0 = *(const float4*)&b1[lane * 8];
    float4 bb1 = *(const float4*)&b1[lane * 8 + 4];

#pragma unroll
    for (int it = 0; it < 4; ++it) {
        int local = it * 64 + nsub;
        int node = node0 + local;
        float sc = 0.f;
        unsigned p0 = 0, p1 = 0, p2 = 0, p3 = 0;
        if (node < N) {
            int beg = rowptr[node];
            int end = rowptr[node + 1];
            sc = rsqrtf((float)(end - beg + 1));
            float a0, a1, a2, a3, a4, a5, a6, a7;
            {
                uint4 u = hsb[(size_t)node * 8 + lane];   // self loop
                a0 = bflo(u.x); a1 = bfhi(u.x);
                a2 = bflo(u.y); a3 = bfhi(u.y);
                a4 = bflo(u.z); a5 = bfhi(u.z);
                a6 = bflo(u.w); a7 = bfhi(u.w);
            }
            for (int base = beg; base < end; base += 16) {
                int i0 = base + lane;
                int i1 = base + 8 + lane;
                int x0 = (i0 < end) ? csr[i0] : 0;
                int x1 = (i1 < end) ? csr[i1] : 0;
                uint4 r[16];
#pragma unroll
                for (int k = 0; k < 8; ++k) {
                    int s = __shfl(x0, k, 8);
                    r[k] = hsb[(size_t)s * 8 + lane];
                }
#pragma unroll
                for (int k = 0; k < 8; ++k) {
                    int s = __shfl(x1, k, 8);
                    r[8 + k] = hsb[(size_t)s * 8 + lane];
                }
                int cnt = min(16, end - base);
#pragma unroll
                for (int k = 0; k < 16; ++k) {
                    if (k < cnt) {
                        uint4 u = r[k];
                        a0 += bflo(u.x); a1 += bfhi(u.x);
                        a2 += bflo(u.y); a3 += bfhi(u.y);
                        a4 += bflo(u.z); a5 += bfhi(u.z);
                        a6 += bflo(u.w); a7 += bfhi(u.w);
                    }
                }
            }
            float o0 = fmaxf(a0 * sc + bb0.x, 0.f), o1 = fmaxf(a1 * sc + bb0.y, 0.f);
            float o2 = fmaxf(a2 * sc + bb0.z, 0.f), o3 = fmaxf(a3 * sc + bb0.w, 0.f);
            float o4 = fmaxf(a4 * sc + bb1.x, 0.f), o5 = fmaxf(a5 * sc + bb1.y, 0.f);
            float o6 = fmaxf(a6 * sc + bb1.z, 0.f), o7 = fmaxf(a7 * sc + bb1.w, 0.f);
            p0 = (unsigned)f2bf(o0) | ((unsigned)f2bf(o1) << 16);
            p1 = (unsigned)f2bf(o2) | ((unsigned)f2bf(o3) << 16);
            p2 = (unsigned)f2bf(o4) | ((unsigned)f2bf(o5) << 16);
            p3 = (unsigned)f2bf(o6) | ((unsigned)f2bf(o7) << 16);
        }
        *(uint4*)&Act[local * 72 + lane * 8] = make_uint4(p0, p1, p2, p3);
        if (lane == 0) sdv[local] = sc;
    }
    __syncthreads();

    // phase 2: act1(bucket) @ W2, scale by dinv, emit hs2 (sliced layout)
    const int w    = t >> 6;                   // 8 waves
    const int l    = t & 63;
    const int l15  = l & 15;
    const int quad = l >> 4;

    bf16x8 bf[4][2];
#pragma unroll
    for (int nt = 0; nt < 4; ++nt)
#pragma unroll
        for (int kc = 0; kc < 2; ++kc)
            bf[nt][kc] = *(const bf16x8*)&Wl[(nt * 16 + l15) * 72 + kc * 32 + quad * 8];

#pragma unroll
    for (int mt = 0; mt < 2; ++mt) {
        int m0 = w * 32 + mt * 16;
        bf16x8 af0 = *(const bf16x8*)&Act[(m0 + l15) * 72 + quad * 8];
        bf16x8 af1 = *(const bf16x8*)&Act[(m0 + l15) * 72 + 32 + quad * 8];
#pragma unroll
        for (int nt = 0; nt < 4; ++nt) {
            f32x4 z = {0.f, 0.f, 0.f, 0.f};
            z = __builtin_amdgcn_mfma_f32_16x16x32_bf16(af0, bf[nt][0], z, 0, 0, 0);
            z = __builtin_amdgcn_mfma_f32_16x16x32_bf16(af1, bf[nt][1], z, 0, 0, 0);
#pragma unroll
            for (int r = 0; r < 4; ++r) {
                int row = m0 + quad * 4 + r;
                int node = node0 + row;
                if (node < N)
                    hs2[((size_t)nt * N + node) * 16 + l15] = f2bf(z[r] * sdv[row]);
            }
        }
    }
}

// ---- launch 7: final aggregate, feature-sliced (R1 best-measured variant) ----
__global__ __launch_bounds__(256) void k_agg2(const unsigned short* __restrict__ hs2,
                                              const int* __restrict__ rowptr,
                                              const int* __restrict__ csr,
                                              const float* __restrict__ dinv,
                                              const float* __restrict__ b,
                                              float* __restrict__ out, int N) {
    const int slice = blockIdx.x & 3;
    const int chunk = blockIdx.x >> 2;
    const int t = threadIdx.x;
    const int node = chunk * 64 + (t >> 2);
    const int lane = t & 3;
    if (node >= N) return;
    const int beg = rowptr[node];
    const int end = rowptr[node + 1];
    const unsigned short* hp = hs2 + (size_t)slice * N * 16;

    float a[16];
#pragma unroll
    for (int j = 0; j < 16; ++j) a[j] = 0.f;

    // software-pipelined gather: indices for iter i+1 load while iter i's rows land
    int e = beg + lane;
    int i0 = (e < end) ? csr[e] : -1;
    int i1 = (e + 4 < end) ? csr[e + 4] : -1;
    while (i0 >= 0) {
        int i2 = (e + 8  < end) ? csr[e + 8]  : -1;
        int i3 = (e + 12 < end) ? csr[e + 12] : -1;
        {
            const uint4* p = (const uint4*)(hp + (size_t)i0 * 16);
            uint4 u0 = p[0];
            uint4 u1 = p[1];
            a[0] += bflo(u0.x); a[1] += bfhi(u0.x);
            a[2] += bflo(u0.y); a[3] += bfhi(u0.y);
            a[4] += bflo(u0.z); a[5] += bfhi(u0.z);
            a[6] += bflo(u0.w); a[7] += bfhi(u0.w);
            a[8]  += bflo(u1.x); a[9]  += bfhi(u1.x);
            a[10] += bflo(u1.y); a[11] += bfhi(u1.y);
            a[12] += bflo(u1.z); a[13] += bfhi(u1.z);
            a[14] += bflo(u1.w); a[15] += bfhi(u1.w);
        }
        if (i1 >= 0) {
            const uint4* p = (const uint4*)(hp + (size_t)i1 * 16);
            uint4 u0 = p[0];
            uint4 u1 = p[1];
            a[0] += bflo(u0.x); a[1] += bfhi(u0.x);
            a[2] += bflo(u0.y); a[3] += bfhi(u0.y);
            a[4] += bflo(u0.z); a[5] += bfhi(u0.z);
            a[6] += bflo(u0.w); a[7] += bfhi(u0.w);
            a[8]  += bflo(u1.x); a[9]  += bfhi(u1.x);
            a[10] += bflo(u1.y); a[11] += bfhi(u1.y);
            a[12] += bflo(u1.z); a[13] += bfhi(u1.z);
            a[14] += bflo(u1.w); a[15] += bfhi(u1.w);
        }
        i0 = i2;
        i1 = i3;
        e += 8;
    }

    // reduce-scatter over the 4-lane group: lane l ends with features l*4..l*4+3.
    float h[8];
#pragma unroll
    for (int k = 0; k < 8; ++k) {
        float lo = a[k]     + __shfl_xor(a[k], 2, 4);
        float hi = a[k + 8] + __shfl_xor(a[k + 8], 2, 4);
        h[k] = (lane & 2) ? hi : lo;
    }
    float v[4];
#pragma unroll
    for (int k = 0; k < 4; ++k) {
        float lo = h[k]     + __shfl_xor(h[k], 1, 4);
        float hi = h[k + 4] + __shfl_xor(h[k + 4], 1, 4);
        v[k] = (lane & 1) ? hi : lo;
    }

    const float sc = dinv[node];
    const int j0 = lane * 4;                   // this lane writes features j0..j0+3
    uint2 sv = *(const uint2*)(hp + (size_t)node * 16 + j0);   // self loop (4 bf16)
    float s0 = bflo(sv.x), s1 = bfhi(sv.x), s2 = bflo(sv.y), s3 = bfhi(sv.y);
    float4 bb = *(const float4*)&b[slice * 16 + j0];
    float4 o = make_float4((v[0] + s0) * sc + bb.x,
                           (v[1] + s1) * sc + bb.y,
                           (v[2] + s2) * sc + bb.z,
                           (v[3] + s3) * sc + bb.w);
    *(float4*)&out[(size_t)node * F + slice * 16 + j0] = o;
}

extern "C" void kernel_launch(void* const* d_in, const int* in_sizes, int n_in,
                              void* d_out, int out_size, void* d_ws, size_t ws_size,
                              hipStream_t stream) {
    const float* x  = (const float*)d_in[0];
    const int*   ei = (const int*)d_in[1];
    const float* W1 = (const float*)d_in[2];
    const float* b1 = (const float*)d_in[3];
    const float* W2 = (const float*)d_in[4];
    const float* b2 = (const float*)d_in[5];
    float* out = (float*)d_out;

    const int N = in_sizes[0] / F;
    const int E = in_sizes[1] / 2;
    const int* src = ei;
    const int* dst = ei + E;

    const int NB = (N + 255) >> 8;                       // buckets (391)
    const int chunk = (E + NCH - 1) / NCH;
    const int M  = NB * NCH;
    const int Mp = ((M + 1023) / 1024) * 1024;
    const int nb2 = Mp / 1024;                           // <= 256

    // ws: W1t | W2t | deg | dinv | part2 | rowptr | histM | ebuf | csr | hs1 | hs2
    char* ws = (char*)d_ws;
    size_t a = 0;
    unsigned short* W1t = (unsigned short*)(ws + a); a += (4096 * 2 + 255) & ~(size_t)255;
    unsigned short* W2t = (unsigned short*)(ws + a); a += (4096 * 2 + 255) & ~(size_t)255;
    int*   deg    = (int*)(ws + a);   a += ((size_t)N * 4 + 255) & ~(size_t)255;
    float* dinv   = (float*)(ws + a); a += ((size_t)N * 4 + 255) & ~(size_t)255;
    int*   part2  = (int*)(ws + a);   a += ((size_t)nb2 * 4 + 255) & ~(size_t)255;
    int*   rowptr = (int*)(ws + a);   a += ((size_t)(N + 1) * 4 + 255) & ~(size_t)255;
    int*   histM  = (int*)(ws + a);   a += ((size_t)Mp * 4 + 255) & ~(size_t)255;
    int*   ebuf   = (int*)(ws + a);   a += ((size_t)E * 4 + 255) & ~(size_t)255;
    int*   csr    = (int*)(ws + a);   a += ((size_t)E * 4 + 255) & ~(size_t)255;
    unsigned short* hs1 = (unsigned short*)(ws + a); a += ((size_t)N * F * 2 + 255) & ~(size_t)255;
    unsigned short* hs2 = (unsigned short*)(ws + a);

    const int gZ    = (N + 1023) / 1024;                 // zero/dinv role blocks (98)
    const int gGemm = (N + 63) / 64;                     // 1563
    const int gAgg2 = ((N + 63) / 64) * 4;               // 4 slices, 64 nodes/block

    // 7-launch schedule; gemm1 rides with scatter (complementary bound-ness)
    k_fused0<<<NCH + 2 + gZ, 256, 0, stream>>>(dst, histM, W1, W2, W1t, W2t, deg,
                                               E, chunk, NB, N);
    k_partdeg<<<nb2 + NCH, 256, 0, stream>>>(histM, part2, dst, deg, M, E, chunk, nb2);
    k_emitdinv<<<nb2 + gZ, 256, 0, stream>>>(histM, part2, deg, dinv, M, N, nb2);
    k_scatgemm<<<NCH + gGemm, 256, 0, stream>>>(src, dst, histM, ebuf, x, W1t, dinv,
                                                hs1, E, chunk, NB, N);
    k_csr<<<NB, 256, 0, stream>>>(ebuf, histM, rowptr, csr, N, E, NB);
    k_aggmm<<<NB, 512, 0, stream>>>(hs1, rowptr, csr, W2t, b1, hs2, N);
    k_agg2<<<gAgg2, 256, 0, stream>>>(hs2, rowptr, csr, dinv, b2, out, N);
}

// Round 6
// 188.532 us; speedup vs baseline: 1.1695x; 1.1695x over previous
//
#include <hip/hip_runtime.h>

#define F 64
#define NCH 256          // edge chunks (= blocks) for hist/scatter passes
// buckets are 256 nodes wide: bucket = dst >> 8. N=100000 -> NB=391
// packing: ebuf entry = src | (dst&255)<<17  (needs N < 131072)

typedef __attribute__((ext_vector_type(8))) short bf16x8;
typedef __attribute__((ext_vector_type(4))) float f32x4;

static __device__ __forceinline__ unsigned short f2bf(float f) {
    unsigned u = __float_as_uint(f);
    return (unsigned short)((u + 0x7fffu + ((u >> 16) & 1u)) >> 16);   // RNE
}
static __device__ __forceinline__ float bflo(unsigned u) { return __uint_as_float(u << 16); }
static __device__ __forceinline__ float bfhi(unsigned u) { return __uint_as_float(u & 0xffff0000u); }

// ---- launch 1 (3 roles): hist + W2 prep + gemm1-unscaled ----
// blocks [0,NCH): per-chunk bucket histogram (latency/atomic-bound)
// block NCH: W2 -> bf16 transposed
// blocks (NCH, NCH+gGemm]: hs1 = X @ W1 UNSCALED bf16 (depends only on raw
//   inputs; W1 converted in-block). R3 measured this fusion at ~+7us; the
//   R3 regression came from its per-EDGE dinv fold (k_aggmm +16us) and R5's
//   from global deg atomics (43us) — both reverted. dinv is applied per-NODE
//   in k_csr below.
__global__ __launch_bounds__(256) void k_fused0(const int* __restrict__ dst,
                                                int* __restrict__ histM,
                                                const float* __restrict__ W1,
                                                const float* __restrict__ W2,
                                                unsigned short* __restrict__ W2t,
                                                const float* __restrict__ X,
                                                unsigned short* __restrict__ hs1,
                                                int E, int chunk, int NB, int N) {
    __shared__ int h[512];                    // NB <= 512
    __shared__ unsigned short Wl[64 * 72];    // W1t bf16, stride 72 (gemm role)
    __shared__ unsigned short Xs[64 * 72];    // X rows bf16 (gemm role)
    const int t = threadIdx.x;
    const int b = blockIdx.x;

    if (b < NCH) {                            // ---- histogram role ----
        for (int i = t; i < NB; i += 256) h[i] = 0;
        __syncthreads();
        const int lo = b * chunk;
        const int hi = min(E, lo + chunk);
        for (int e = lo + t; e < hi; e += 256) {
            atomicAdd(&h[dst[e] >> 8], 1);
        }
        __syncthreads();
        for (int i = t; i < NB; i += 256) histM[i * NCH + b] = h[i];
        return;
    }
    if (b == NCH) {                           // ---- W2 prep role ----
#pragma unroll
        for (int i = 0; i < 16; ++i) {
            int e = t + i * 256;
            int n = e >> 6, k = e & 63;
            W2t[e] = f2bf(W2[k * 64 + n]);
        }
        return;
    }

    // ---- gemm role: rows [row0, row0+64) of hs1 = X @ W1 (bf16, unscaled) ----
    const int row0 = (b - NCH - 1) * 64;
#pragma unroll
    for (int i = 0; i < 16; ++i) {            // W1 fp32 (16KB, L2-hot) -> Wl bf16 T
        int e = t + i * 256;
        int n = e >> 6, k = e & 63;
        Wl[n * 72 + k] = f2bf(W1[k * 64 + n]);
    }
#pragma unroll
    for (int i = 0; i < 4; ++i) {
        int idx = t + i * 256;
        int r = idx >> 4, c = (idx & 15) * 4;
        int gr = row0 + r;
        float4 v = make_float4(0.f, 0.f, 0.f, 0.f);
        if (gr < N) v = *(const float4*)&X[(size_t)gr * F + c];
        unsigned p0 = (unsigned)f2bf(v.x) | ((unsigned)f2bf(v.y) << 16);
        unsigned p1 = (unsigned)f2bf(v.z) | ((unsigned)f2bf(v.w) << 16);
        *(uint2*)&Xs[r * 72 + c] = make_uint2(p0, p1);
    }
    __syncthreads();

    const int w    = t >> 6;
    const int lane = t & 63;
    const int l15  = lane & 15;
    const int quad = lane >> 4;

    bf16x8 bf[4][2];
#pragma unroll
    for (int ct = 0; ct < 4; ++ct)
#pragma unroll
        for (int kc = 0; kc < 2; ++kc)
            bf[ct][kc] = *(const bf16x8*)&Wl[(ct * 16 + l15) * 72 + kc * 32 + quad * 8];

    const int am = w * 16 + l15;
    bf16x8 af0 = *(const bf16x8*)&Xs[am * 72 + quad * 8];
    bf16x8 af1 = *(const bf16x8*)&Xs[am * 72 + 32 + quad * 8];

    f32x4 acc[4];
#pragma unroll
    for (int ct = 0; ct < 4; ++ct) {
        f32x4 z = {0.f, 0.f, 0.f, 0.f};
        z = __builtin_amdgcn_mfma_f32_16x16x32_bf16(af0, bf[ct][0], z, 0, 0, 0);
        z = __builtin_amdgcn_mfma_f32_16x16x32_bf16(af1, bf[ct][1], z, 0, 0, 0);
        acc[ct] = z;
    }

#pragma unroll
    for (int ct = 0; ct < 4; ++ct) {
#pragma unroll
        for (int r = 0; r < 4; ++r) {
            int row = row0 + w * 16 + quad * 4 + r;
            if (row < N)
                hs1[(size_t)row * F + ct * 16 + l15] = f2bf(acc[ct][r]);
        }
    }
}

// ---- launch 2: per-1024 partial sums of histM ----
__global__ __launch_bounds__(256) void s_part(const int* __restrict__ v,
                                              int* __restrict__ part, int M) {
    __shared__ int sd[256];
    const int t = threadIdx.x;
    const int base = blockIdx.x * 1024 + t * 4;
    int s = 0;
    if (base + 3 < M) {
        int4 d = *(const int4*)&v[base];
        s = d.x + d.y + d.z + d.w;
    } else {
#pragma unroll
        for (int j = 0; j < 4; ++j) if (base + j < M) s += v[base + j];
    }
    sd[t] = s;
    __syncthreads();
    for (int off = 128; off > 0; off >>= 1) {
        if (t < off) sd[t] += sd[t + off];
        __syncthreads();
    }
    if (t == 0) part[blockIdx.x] = sd[0];
}

// ---- launch 3: emit with INLINE prefix of raw partials (merges s_scanp) ----
// each block reduces part[0..b) itself; nb <= 256. (validated in R5)
__global__ __launch_bounds__(256) void s_emit2(int* __restrict__ v,
                                               const int* __restrict__ part, int M) {
    __shared__ int sums[256];
    __shared__ int red[256];
    const int t = threadIdx.x;
    const int b = blockIdx.x;

    red[t] = (t < b) ? part[t] : 0;
    __syncthreads();
    for (int off = 128; off > 0; off >>= 1) {
        if (t < off) red[t] += red[t + off];
        __syncthreads();
    }
    const int pref = red[0];

    const int base = b * 1024 + t * 4;
    int d0 = 0, d1 = 0, d2 = 0, d3 = 0;
    if (base + 3 < M) {
        int4 d = *(const int4*)&v[base];
        d0 = d.x; d1 = d.y; d2 = d.z; d3 = d.w;
    } else {
        if (base + 0 < M) d0 = v[base + 0];
        if (base + 1 < M) d1 = v[base + 1];
        if (base + 2 < M) d2 = v[base + 2];
        if (base + 3 < M) d3 = v[base + 3];
    }
    int tot = d0 + d1 + d2 + d3;
    sums[t] = tot;
    __syncthreads();
    for (int off = 1; off < 256; off <<= 1) {
        int x = (t >= off) ? sums[t - off] : 0;
        __syncthreads();
        sums[t] += x;
        __syncthreads();
    }
    int o0 = pref + sums[t] - tot;
    int e0 = o0, e1 = o0 + d0, e2 = e1 + d1, e3 = e2 + d2;
    if (base + 3 < M) {
        *(int4*)&v[base] = make_int4(e0, e1, e2, e3);
    } else {
        int ee[4] = {e0, e1, e2, e3};
        for (int j = 0; j < 4; ++j) if (base + j < M) v[base + j] = ee[j];
    }
}

// ---- launch 4: scatter packed edges into per-(bucket,block)-private regions ----
__global__ __launch_bounds__(256) void k_scatter2(const int* __restrict__ src,
                                                  const int* __restrict__ dst,
                                                  const int* __restrict__ scanM,
                                                  int* __restrict__ ebuf,
                                                  int E, int chunk, int NB) {
    extern __shared__ int cur[];
    const int t = threadIdx.x;
    for (int i = t; i < NB; i += 256) cur[i] = scanM[i * NCH + blockIdx.x];
    __syncthreads();
    const int lo = blockIdx.x * chunk;
    const int hi = min(E, lo + chunk);
    for (int e = lo + t; e < hi; e += 256) {
        int s = src[e];
        int d = dst[e];
        int p = atomicAdd(&cur[d >> 8], 1);
        ebuf[p] = s | ((d & 255) << 17);
    }
}

// ---- launch 5: per-bucket counting sort -> rowptr, dinv, csr  +  hs1 *= dinv ----
// Each bucket block owns nodes [bkt*256, bkt*256+256): their degree (hist[t]) is
// local, so it scales ITS OWN nodes' hs1 rows in-place — no cross-block dep.
// This moves the dinv scaling off gemm1 (enabling launch-1 fusion) at per-NODE
// cost (25.6MB streamed), not R3's per-edge cost.
__global__ __launch_bounds__(256) void k_csr(const int* __restrict__ ebuf,
                                             const int* __restrict__ scanM,
                                             int* __restrict__ rowptr,
                                             int* __restrict__ csr,
                                             float* __restrict__ dinv,
                                             unsigned short* __restrict__ hs1,
                                             int N, int E, int NB) {
    __shared__ int hist[256];
    __shared__ int scn[256];
    __shared__ int cur[256];
    const int t = threadIdx.x;
    const int bkt = blockIdx.x;
    const int beg = scanM[bkt * NCH];
    const int end = (bkt + 1 < NB) ? scanM[(bkt + 1) * NCH] : E;

    hist[t] = 0;
    __syncthreads();
    for (int e = beg + t; e < end; e += 256)
        atomicAdd(&hist[((unsigned)ebuf[e]) >> 17], 1);
    __syncthreads();

    scn[t] = hist[t];
    __syncthreads();
    for (int off = 1; off < 256; off <<= 1) {
        int v = (t >= off) ? scn[t - off] : 0;
        __syncthreads();
        scn[t] += v;
        __syncthreads();
    }

    const int node = (bkt << 8) + t;
    float sc = 0.f;
    {
        int excl = scn[t] - hist[t];
        int rp = beg + excl;
        cur[t] = rp;
        if (node < N) {
            rowptr[node] = rp;
            sc = rsqrtf((float)(hist[t] + 1));   // +1 self loop
            dinv[node] = sc;
        }
    }
    if (bkt == NB - 1 && t == 0) rowptr[N] = E;

    // scale own node's hs1 row in place (64 bf16 = 8 uint4)
    if (node < N) {
        uint4* rowp = (uint4*)(hs1 + (size_t)node * F);
#pragma unroll
        for (int j = 0; j < 8; ++j) {
            uint4 u = rowp[j];
            u.x = (unsigned)f2bf(bflo(u.x) * sc) | ((unsigned)f2bf(bfhi(u.x) * sc) << 16);
            u.y = (unsigned)f2bf(bflo(u.y) * sc) | ((unsigned)f2bf(bfhi(u.y) * sc) << 16);
            u.z = (unsigned)f2bf(bflo(u.z) * sc) | ((unsigned)f2bf(bfhi(u.z) * sc) << 16);
            u.w = (unsigned)f2bf(bflo(u.w) * sc) | ((unsigned)f2bf(bfhi(u.w) * sc) << 16);
            rowp[j] = u;
        }
    }
    __syncthreads();

    for (int e = beg + t; e < end; e += 256) {
        int pk = ebuf[e];
        int p = atomicAdd(&cur[((unsigned)pk) >> 17], 1);
        csr[p] = pk & 0x1FFFF;
    }
}

// ---- launch 6: fused agg1 + gemm2 (R1 best-measured variant, 256-node buckets) ----
// hs2 emitted in SLICED layout: hs2[(slice*N + node)*16 + pos], slice=feature>>4.
__global__ __launch_bounds__(512) void k_aggmm(const unsigned short* __restrict__ hs1,
                                               const int* __restrict__ rowptr,
                                               const int* __restrict__ csr,
                                               const unsigned short* __restrict__ W2t,
                                               const float* __restrict__ b1,
                                               unsigned short* __restrict__ hs2, int N) {
    __shared__ unsigned short Act[256 * 72];   // act1 bf16, stride 72
    __shared__ unsigned short Wl[64 * 72];     // W2t padded
    __shared__ float sdv[256];                 // per-node dinv
    const int t = threadIdx.x;
    const int node0 = blockIdx.x << 8;

    {
        int idx = t;                           // 512 uint4 = full 4096 bf16
        int n = idx >> 3, k = (idx & 7) * 8;
        *(uint4*)&Wl[n * 72 + k] = ((const uint4*)W2t)[idx];
    }

    const int lane = t & 7;
    const int nsub = t >> 3;                   // 0..63
    const uint4* hsb = (const uint4*)hs1;
    float4 bb0 = *(const float4*)&b1[lane * 8];
    float4 bb1 = *(const float4*)&b1[lane * 8 + 4];

#pragma unroll
    for (int it = 0; it < 4; ++it) {
        int local = it * 64 + nsub;
        int node = node0 + local;
        float sc = 0.f;
        unsigned p0 = 0, p1 = 0, p2 = 0, p3 = 0;
        if (node < N) {
            int beg = rowptr[node];
            int end = rowptr[node + 1];
            sc = rsqrtf((float)(end - beg + 1));
            float a0, a1, a2, a3, a4, a5, a6, a7;
            {
                uint4 u = hsb[(size_t)node * 8 + lane];   // self loop
                a0 = bflo(u.x); a1 = bfhi(u.x);
                a2 = bflo(u.y); a3 = bfhi(u.y);
                a4 = bflo(u.z); a5 = bfhi(u.z);
                a6 = bflo(u.w); a7 = bfhi(u.w);
            }
            for (int base = beg; base < end; base += 16) {
                int i0 = base + lane;
                int i1 = base + 8 + lane;
                int x0 = (i0 < end) ? csr[i0] : 0;
                int x1 = (i1 < end) ? csr[i1] : 0;
                uint4 r[16];
#pragma unroll
                for (int k = 0; k < 8; ++k) {
                    int s = __shfl(x0, k, 8);
                    r[k] = hsb[(size_t)s * 8 + lane];
                }
#pragma unroll
                for (int k = 0; k < 8; ++k) {
                    int s = __shfl(x1, k, 8);
                    r[8 + k] = hsb[(size_t)s * 8 + lane];
                }
                int cnt = min(16, end - base);
#pragma unroll
                for (int k = 0; k < 16; ++k) {
                    if (k < cnt) {
                        uint4 u = r[k];
                        a0 += bflo(u.x); a1 += bfhi(u.x);
                        a2 += bflo(u.y); a3 += bfhi(u.y);
                        a4 += bflo(u.z); a5 += bfhi(u.z);
                        a6 += bflo(u.w); a7 += bfhi(u.w);
                    }
                }
            }
            float o0 = fmaxf(a0 * sc + bb0.x, 0.f), o1 = fmaxf(a1 * sc + bb0.y, 0.f);
            float o2 = fmaxf(a2 * sc + bb0.z, 0.f), o3 = fmaxf(a3 * sc + bb0.w, 0.f);
            float o4 = fmaxf(a4 * sc + bb1.x, 0.f), o5 = fmaxf(a5 * sc + bb1.y, 0.f);
            float o6 = fmaxf(a6 * sc + bb1.z, 0.f), o7 = fmaxf(a7 * sc + bb1.w, 0.f);
            p0 = (unsigned)f2bf(o0) | ((unsigned)f2bf(o1) << 16);
            p1 = (unsigned)f2bf(o2) | ((unsigned)f2bf(o3) << 16);
            p2 = (unsigned)f2bf(o4) | ((unsigned)f2bf(o5) << 16);
            p3 = (unsigned)f2bf(o6) | ((unsigned)f2bf(o7) << 16);
        }
        *(uint4*)&Act[local * 72 + lane * 8] = make_uint4(p0, p1, p2, p3);
        if (lane == 0) sdv[local] = sc;
    }
    __syncthreads();

    // phase 2: act1(bucket) @ W2, scale by dinv, emit hs2 (sliced layout)
    const int w    = t >> 6;                   // 8 waves
    const int l    = t & 63;
    const int l15  = l & 15;
    const int quad = l >> 4;

    bf16x8 bf[4][2];
#pragma unroll
    for (int nt = 0; nt < 4; ++nt)
#pragma unroll
        for (int kc = 0; kc < 2; ++kc)
            bf[nt][kc] = *(const bf16x8*)&Wl[(nt * 16 + l15) * 72 + kc * 32 + quad * 8];

#pragma unroll
    for (int mt = 0; mt < 2; ++mt) {
        int m0 = w * 32 + mt * 16;
        bf16x8 af0 = *(const bf16x8*)&Act[(m0 + l15) * 72 + quad * 8];
        bf16x8 af1 = *(const bf16x8*)&Act[(m0 + l15) * 72 + 32 + quad * 8];
#pragma unroll
        for (int nt = 0; nt < 4; ++nt) {
            f32x4 z = {0.f, 0.f, 0.f, 0.f};
            z = __builtin_amdgcn_mfma_f32_16x16x32_bf16(af0, bf[nt][0], z, 0, 0, 0);
            z = __builtin_amdgcn_mfma_f32_16x16x32_bf16(af1, bf[nt][1], z, 0, 0, 0);
#pragma unroll
            for (int r = 0; r < 4; ++r) {
                int row = m0 + quad * 4 + r;
                int node = node0 + row;
                if (node < N)
                    hs2[((size_t)nt * N + node) * 16 + l15] = f2bf(z[r] * sdv[row]);
            }
        }
    }
}

// ---- launch 7: final aggregate, feature-sliced (R1 best-measured variant) ----
__global__ __launch_bounds__(256) void k_agg2(const unsigned short* __restrict__ hs2,
                                              const int* __restrict__ rowptr,
                                              const int* __restrict__ csr,
                                              const float* __restrict__ dinv,
                                              const float* __restrict__ b,
                                              float* __restrict__ out, int N) {
    const int slice = blockIdx.x & 3;
    const int chunk = blockIdx.x >> 2;
    const int t = threadIdx.x;
    const int node = chunk * 64 + (t >> 2);
    const int lane = t & 3;
    if (node >= N) return;
    const int beg = rowptr[node];
    const int end = rowptr[node + 1];
    const unsigned short* hp = hs2 + (size_t)slice * N * 16;

    float a[16];
#pragma unroll
    for (int j = 0; j < 16; ++j) a[j] = 0.f;

    // software-pipelined gather: indices for iter i+1 load while iter i's rows land
    int e = beg + lane;
    int i0 = (e < end) ? csr[e] : -1;
    int i1 = (e + 4 < end) ? csr[e + 4] : -1;
    while (i0 >= 0) {
        int i2 = (e + 8  < end) ? csr[e + 8]  : -1;
        int i3 = (e + 12 < end) ? csr[e + 12] : -1;
        {
            const uint4* p = (const uint4*)(hp + (size_t)i0 * 16);
            uint4 u0 = p[0];
            uint4 u1 = p[1];
            a[0] += bflo(u0.x); a[1] += bfhi(u0.x);
            a[2] += bflo(u0.y); a[3] += bfhi(u0.y);
            a[4] += bflo(u0.z); a[5] += bfhi(u0.z);
            a[6] += bflo(u0.w); a[7] += bfhi(u0.w);
            a[8]  += bflo(u1.x); a[9]  += bfhi(u1.x);
            a[10] += bflo(u1.y); a[11] += bfhi(u1.y);
            a[12] += bflo(u1.z); a[13] += bfhi(u1.z);
            a[14] += bflo(u1.w); a[15] += bfhi(u1.w);
        }
        if (i1 >= 0) {
            const uint4* p = (const uint4*)(hp + (size_t)i1 * 16);
            uint4 u0 = p[0];
            uint4 u1 = p[1];
            a[0] += bflo(u0.x); a[1] += bfhi(u0.x);
            a[2] += bflo(u0.y); a[3] += bfhi(u0.y);
            a[4] += bflo(u0.z); a[5] += bfhi(u0.z);
            a[6] += bflo(u0.w); a[7] += bfhi(u0.w);
            a[8]  += bflo(u1.x); a[9]  += bfhi(u1.x);
            a[10] += bflo(u1.y); a[11] += bfhi(u1.y);
            a[12] += bflo(u1.z); a[13] += bfhi(u1.z);
            a[14] += bflo(u1.w); a[15] += bfhi(u1.w);
        }
        i0 = i2;
        i1 = i3;
        e += 8;
    }

    // reduce-scatter over the 4-lane group: lane l ends with features l*4..l*4+3.
    float h[8];
#pragma unroll
    for (int k = 0; k < 8; ++k) {
        float lo = a[k]     + __shfl_xor(a[k], 2, 4);
        float hi = a[k + 8] + __shfl_xor(a[k + 8], 2, 4);
        h[k] = (lane & 2) ? hi : lo;
    }
    float v[4];
#pragma unroll
    for (int k = 0; k < 4; ++k) {
        float lo = h[k]     + __shfl_xor(h[k], 1, 4);
        float hi = h[k + 4] + __shfl_xor(h[k + 4], 1, 4);
        v[k] = (lane & 1) ? hi : lo;
    }

    const float sc = dinv[node];
    const int j0 = lane * 4;                   // this lane writes features j0..j0+3
    uint2 sv = *(const uint2*)(hp + (size_t)node * 16 + j0);   // self loop (4 bf16)
    float s0 = bflo(sv.x), s1 = bfhi(sv.x), s2 = bflo(sv.y), s3 = bfhi(sv.y);
    float4 bb = *(const float4*)&b[slice * 16 + j0];
    float4 o = make_float4((v[0] + s0) * sc + bb.x,
                           (v[1] + s1) * sc + bb.y,
                           (v[2] + s2) * sc + bb.z,
                           (v[3] + s3) * sc + bb.w);
    *(float4*)&out[(size_t)node * F + slice * 16 + j0] = o;
}

extern "C" void kernel_launch(void* const* d_in, const int* in_sizes, int n_in,
                              void* d_out, int out_size, void* d_ws, size_t ws_size,
                              hipStream_t stream) {
    const float* x  = (const float*)d_in[0];
    const int*   ei = (const int*)d_in[1];
    const float* W1 = (const float*)d_in[2];
    const float* b1 = (const float*)d_in[3];
    const float* W2 = (const float*)d_in[4];
    const float* b2 = (const float*)d_in[5];
    float* out = (float*)d_out;

    const int N = in_sizes[0] / F;
    const int E = in_sizes[1] / 2;
    const int* src = ei;
    const int* dst = ei + E;

    const int NB = (N + 255) >> 8;                       // buckets (391)
    const int chunk = (E + NCH - 1) / NCH;
    const int M  = NB * NCH;
    const int Mp = ((M + 1023) / 1024) * 1024;
    const int nb2 = Mp / 1024;                           // <= 256

    // ws: W2t | dinv | part2 | rowptr | histM | ebuf | csr | hs1 | hs2
    char* ws = (char*)d_ws;
    size_t a = 0;
    unsigned short* W2t = (unsigned short*)(ws + a); a += (4096 * 2 + 255) & ~(size_t)255;
    float* dinv   = (float*)(ws + a); a += ((size_t)N * 4 + 255) & ~(size_t)255;
    int*   part2  = (int*)(ws + a);   a += ((size_t)nb2 * 4 + 255) & ~(size_t)255;
    int*   rowptr = (int*)(ws + a);   a += ((size_t)(N + 1) * 4 + 255) & ~(size_t)255;
    int*   histM  = (int*)(ws + a);   a += ((size_t)Mp * 4 + 255) & ~(size_t)255;
    int*   ebuf   = (int*)(ws + a);   a += ((size_t)E * 4 + 255) & ~(size_t)255;
    int*   csr    = (int*)(ws + a);   a += ((size_t)E * 4 + 255) & ~(size_t)255;
    unsigned short* hs1 = (unsigned short*)(ws + a); a += ((size_t)N * F * 2 + 255) & ~(size_t)255;
    unsigned short* hs2 = (unsigned short*)(ws + a);

    const size_t ldsNB = (size_t)NB * 4;
    const int gGemm = (N + 63) / 64;                     // 1563
    const int gAgg2 = ((N + 63) / 64) * 4;               // 4 slices, 64 nodes/block

    // 7-launch schedule; gemm1 rides with hist (R3's proven fusion, minus its
    // per-edge dinv mistake), scanp inlined into emit (R5-validated).
    k_fused0<<<NCH + 1 + gGemm, 256, 0, stream>>>(dst, histM, W1, W2, W2t, x, hs1,
                                                  E, chunk, NB, N);
    s_part<<<nb2, 256, 0, stream>>>(histM, part2, M);
    s_emit2<<<nb2, 256, 0, stream>>>(histM, part2, M);
    k_scatter2<<<NCH, 256, ldsNB, stream>>>(src, dst, histM, ebuf, E, chunk, NB);
    k_csr<<<NB, 256, 0, stream>>>(ebuf, histM, rowptr, csr, dinv, hs1, N, E, NB);
    k_aggmm<<<NB, 512, 0, stream>>>(hs1, rowptr, csr, W2t, b1, hs2, N);
    k_agg2<<<gAgg2, 256, 0, stream>>>(hs2, rowptr, csr, dinv, b2, out, N);
}

// Round 8
// 180.817 us; speedup vs baseline: 1.2194x; 1.0427x over previous
//
#include <hip/hip_runtime.h>

#define F 64
#define NCH 256          // edge chunks (= blocks) for hist/scatter passes
// buckets are 256 nodes wide: bucket = dst >> 8. N=100000 -> NB=391
// packing: ebuf entry = src | (dst&255)<<17  (needs N < 131072)

typedef __attribute__((ext_vector_type(8))) short bf16x8;
typedef __attribute__((ext_vector_type(4))) float f32x4;

static __device__ __forceinline__ unsigned short f2bf(float f) {
    unsigned u = __float_as_uint(f);
    return (unsigned short)((u + 0x7fffu + ((u >> 16) & 1u)) >> 16);   // RNE
}
static __device__ __forceinline__ float bflo(unsigned u) { return __uint_as_float(u << 16); }
static __device__ __forceinline__ float bfhi(unsigned u) { return __uint_as_float(u & 0xffff0000u); }

// ---- pass A: per-chunk bucket histogram (blocks 0..NCH-1) + weight prep (last 2 blocks) ----
__global__ __launch_bounds__(256) void k_histprep(const int* __restrict__ dst,
                                                  int* __restrict__ histM,
                                                  const float* __restrict__ W1,
                                                  const float* __restrict__ W2,
                                                  unsigned short* __restrict__ W1t,
                                                  unsigned short* __restrict__ W2t,
                                                  int E, int chunk, int NB) {
    const int t = threadIdx.x;
    if (blockIdx.x >= NCH) {                 // weight prep: W -> bf16 transposed [n*64+k]
        int which = blockIdx.x - NCH;
        const float* W = which ? W2 : W1;
        unsigned short* Wt = which ? W2t : W1t;
#pragma unroll
        for (int i = 0; i < 16; ++i) {
            int e = t + i * 256;
            int n = e >> 6, k = e & 63;
            Wt[e] = f2bf(W[k * 64 + n]);
        }
        return;
    }
    extern __shared__ int h[];
    for (int i = t; i < NB; i += 256) h[i] = 0;
    __syncthreads();
    const int lo = blockIdx.x * chunk;
    const int hi = min(E, lo + chunk);
    for (int e = lo + t; e < hi; e += 256) {
        atomicAdd(&h[dst[e] >> 8], 1);
    }
    __syncthreads();
    for (int i = t; i < NB; i += 256) histM[i * NCH + blockIdx.x] = h[i];
}

// ---- pass B1: per-1024 partial sums of histM ----
__global__ __launch_bounds__(256) void s_part(const int* __restrict__ v,
                                              int* __restrict__ part, int M) {
    __shared__ int sd[256];
    const int t = threadIdx.x;
    const int base = blockIdx.x * 1024 + t * 4;
    int s = 0;
    if (base + 3 < M) {
        int4 d = *(const int4*)&v[base];
        s = d.x + d.y + d.z + d.w;
    } else {
#pragma unroll
        for (int j = 0; j < 4; ++j) if (base + j < M) s += v[base + j];
    }
    sd[t] = s;
    __syncthreads();
    for (int off = 128; off > 0; off >>= 1) {
        if (t < off) sd[t] += sd[t + off];
        __syncthreads();
    }
    if (t == 0) part[blockIdx.x] = sd[0];
}

// ---- pass B2: emit with INLINE prefix of raw partials (merges old s_scanp) ----
// each block reduces part[0..b) itself; nb <= 256. Functionally validated in
// R5/R6; saves one launch vs the 3-stage scan.
__global__ __launch_bounds__(256) void s_emit2(int* __restrict__ v,
                                               const int* __restrict__ part, int M) {
    __shared__ int sums[256];
    __shared__ int red[256];
    const int t = threadIdx.x;
    const int b = blockIdx.x;

    red[t] = (t < b) ? part[t] : 0;
    __syncthreads();
    for (int off = 128; off > 0; off >>= 1) {
        if (t < off) red[t] += red[t + off];
        __syncthreads();
    }
    const int pref = red[0];

    const int base = b * 1024 + t * 4;
    int d0 = 0, d1 = 0, d2 = 0, d3 = 0;
    if (base + 3 < M) {
        int4 d = *(const int4*)&v[base];
        d0 = d.x; d1 = d.y; d2 = d.z; d3 = d.w;
    } else {
        if (base + 0 < M) d0 = v[base + 0];
        if (base + 1 < M) d1 = v[base + 1];
        if (base + 2 < M) d2 = v[base + 2];
        if (base + 3 < M) d3 = v[base + 3];
    }
    int tot = d0 + d1 + d2 + d3;
    sums[t] = tot;
    __syncthreads();
    for (int off = 1; off < 256; off <<= 1) {
        int x = (t >= off) ? sums[t - off] : 0;
        __syncthreads();
        sums[t] += x;
        __syncthreads();
    }
    int o0 = pref + sums[t] - tot;
    int e0 = o0, e1 = o0 + d0, e2 = e1 + d1, e3 = e2 + d2;
    if (base + 3 < M) {
        *(int4*)&v[base] = make_int4(e0, e1, e2, e3);
    } else {
        int ee[4] = {e0, e1, e2, e3};
        for (int j = 0; j < 4; ++j) if (base + j < M) v[base + j] = ee[j];
    }
}

// ---- pass C: scatter packed edges into per-(bucket,block)-private regions ----
__global__ __launch_bounds__(256) void k_scatter2(const int* __restrict__ src,
                                                  const int* __restrict__ dst,
                                                  const int* __restrict__ scanM,
                                                  int* __restrict__ ebuf,
                                                  int E, int chunk, int NB) {
    extern __shared__ int cur[];
    const int t = threadIdx.x;
    for (int i = t; i < NB; i += 256) cur[i] = scanM[i * NCH + blockIdx.x];
    __syncthreads();
    const int lo = blockIdx.x * chunk;
    const int hi = min(E, lo + chunk);
    for (int e = lo + t; e < hi; e += 256) {
        int s = src[e];
        int d = dst[e];
        int p = atomicAdd(&cur[d >> 8], 1);
        ebuf[p] = s | ((d & 255) << 17);
    }
}

// ---- pass D: per-bucket LDS counting sort -> rowptr, dinv, node-sorted csr ----
__global__ __launch_bounds__(256) void k_csr(const int* __restrict__ ebuf,
                                             const int* __restrict__ scanM,
                                             int* __restrict__ rowptr,
                                             int* __restrict__ csr,
                                             float* __restrict__ dinv,
                                             int N, int E, int NB) {
    __shared__ int hist[256];
    __shared__ int scn[256];
    __shared__ int cur[256];
    const int t = threadIdx.x;
    const int bkt = blockIdx.x;
    const int beg = scanM[bkt * NCH];
    const int end = (bkt + 1 < NB) ? scanM[(bkt + 1) * NCH] : E;

    hist[t] = 0;
    __syncthreads();
    for (int e = beg + t; e < end; e += 256)
        atomicAdd(&hist[((unsigned)ebuf[e]) >> 17], 1);
    __syncthreads();

    scn[t] = hist[t];
    __syncthreads();
    for (int off = 1; off < 256; off <<= 1) {
        int v = (t >= off) ? scn[t - off] : 0;
        __syncthreads();
        scn[t] += v;
        __syncthreads();
    }

    {
        int excl = scn[t] - hist[t];
        int rp = beg + excl;
        int node = (bkt << 8) + t;
        cur[t] = rp;
        if (node < N) {
            rowptr[node] = rp;
            dinv[node] = rsqrtf((float)(hist[t] + 1));   // +1 self loop
        }
    }
    if (bkt == NB - 1 && t == 0) rowptr[N] = E;
    __syncthreads();

    for (int e = beg + t; e < end; e += 256) {
        int pk = ebuf[e];
        int p = atomicAdd(&cur[((unsigned)pk) >> 17], 1);
        csr[p] = pk & 0x1FFFF;
    }
}

// ---- hs1(bf16) = (X @ W1) * dinv[row] via MFMA (W1t pre-converted bf16) ----
__global__ __launch_bounds__(256) void k_gemm1(const float* __restrict__ X,
                                               const unsigned short* __restrict__ W1t,
                                               const float* __restrict__ dinv,
                                               unsigned short* __restrict__ hs, int N) {
    __shared__ unsigned short Wl[64 * 72];   // Wt[n][k], stride 72
    __shared__ unsigned short Xs[64 * 72];   // Xs[r][k], stride 72
    const int t = threadIdx.x;
    const int row0 = blockIdx.x * 64;

#pragma unroll
    for (int i = 0; i < 2; ++i) {
        int idx = t + i * 256;
        int n = idx >> 3, k = (idx & 7) * 8;
        *(uint4*)&Wl[n * 72 + k] = ((const uint4*)W1t)[idx];
    }
#pragma unroll
    for (int i = 0; i < 4; ++i) {
        int idx = t + i * 256;
        int r = idx >> 4, c = (idx & 15) * 4;
        int gr = row0 + r;
        float4 v = make_float4(0.f, 0.f, 0.f, 0.f);
        if (gr < N) v = *(const float4*)&X[(size_t)gr * F + c];
        unsigned p0 = (unsigned)f2bf(v.x) | ((unsigned)f2bf(v.y) << 16);
        unsigned p1 = (unsigned)f2bf(v.z) | ((unsigned)f2bf(v.w) << 16);
        *(uint2*)&Xs[r * 72 + c] = make_uint2(p0, p1);
    }
    __syncthreads();

    const int w    = t >> 6;
    const int lane = t & 63;
    const int l15  = lane & 15;
    const int quad = lane >> 4;

    bf16x8 bf[4][2];
#pragma unroll
    for (int ct = 0; ct < 4; ++ct)
#pragma unroll
        for (int kc = 0; kc < 2; ++kc)
            bf[ct][kc] = *(const bf16x8*)&Wl[(ct * 16 + l15) * 72 + kc * 32 + quad * 8];

    const int am = w * 16 + l15;
    bf16x8 af0 = *(const bf16x8*)&Xs[am * 72 + quad * 8];
    bf16x8 af1 = *(const bf16x8*)&Xs[am * 72 + 32 + quad * 8];

    f32x4 acc[4];
#pragma unroll
    for (int ct = 0; ct < 4; ++ct) {
        f32x4 z = {0.f, 0.f, 0.f, 0.f};
        z = __builtin_amdgcn_mfma_f32_16x16x32_bf16(af0, bf[ct][0], z, 0, 0, 0);
        z = __builtin_amdgcn_mfma_f32_16x16x32_bf16(af1, bf[ct][1], z, 0, 0, 0);
        acc[ct] = z;
    }

    float dv[4];
#pragma unroll
    for (int r = 0; r < 4; ++r) {
        int row = row0 + w * 16 + quad * 4 + r;
        dv[r] = (row < N) ? dinv[row] : 0.f;
    }
#pragma unroll
    for (int ct = 0; ct < 4; ++ct) {
#pragma unroll
        for (int r = 0; r < 4; ++r) {
            int row = row0 + w * 16 + quad * 4 + r;
            if (row < N)
                hs[(size_t)row * F + ct * 16 + l15] = f2bf(acc[ct][r] * dv[r]);
        }
    }
}

// ---- fused agg1 + gemm2 (R1 best-measured variant, 256-node buckets) ----
// hs2 emitted in SLICED layout: hs2[(slice*N + node)*16 + pos], slice=feature>>4.
__global__ __launch_bounds__(512) void k_aggmm(const unsigned short* __restrict__ hs1,
                                               const int* __restrict__ rowptr,
                                               const int* __restrict__ csr,
                                               const unsigned short* __restrict__ W2t,
                                               const float* __restrict__ b1,
                                               unsigned short* __restrict__ hs2, int N) {
    __shared__ unsigned short Act[256 * 72];   // act1 bf16, stride 72
    __shared__ unsigned short Wl[64 * 72];     // W2t padded
    __shared__ float sdv[256];                 // per-node dinv
    const int t = threadIdx.x;
    const int node0 = blockIdx.x << 8;

    {
        int idx = t;                           // 512 uint4 = full 4096 bf16
        int n = idx >> 3, k = (idx & 7) * 8;
        *(uint4*)&Wl[n * 72 + k] = ((const uint4*)W2t)[idx];
    }

    const int lane = t & 7;
    const int nsub = t >> 3;                   // 0..63
    const uint4* hsb = (const uint4*)hs1;
    float4 bb0 = *(const float4*)&b1[lane * 8];
    float4 bb1 = *(const float4*)&b1[lane * 8 + 4];

#pragma unroll
    for (int it = 0; it < 4; ++it) {
        int local = it * 64 + nsub;
        int node = node0 + local;
        float sc = 0.f;
        unsigned p0 = 0, p1 = 0, p2 = 0, p3 = 0;
        if (node < N) {
            int beg = rowptr[node];
            int end = rowptr[node + 1];
            sc = rsqrtf((float)(end - beg + 1));
            float a0, a1, a2, a3, a4, a5, a6, a7;
            {
                uint4 u = hsb[(size_t)node * 8 + lane];   // self loop
                a0 = bflo(u.x); a1 = bfhi(u.x);
                a2 = bflo(u.y); a3 = bfhi(u.y);
                a4 = bflo(u.z); a5 = bfhi(u.z);
                a6 = bflo(u.w); a7 = bfhi(u.w);
            }
            for (int base = beg; base < end; base += 16) {
                int i0 = base + lane;
                int i1 = base + 8 + lane;
                int x0 = (i0 < end) ? csr[i0] : 0;
                int x1 = (i1 < end) ? csr[i1] : 0;
                uint4 r[16];
#pragma unroll
                for (int k = 0; k < 8; ++k) {
                    int s = __shfl(x0, k, 8);
                    r[k] = hsb[(size_t)s * 8 + lane];
                }
#pragma unroll
                for (int k = 0; k < 8; ++k) {
                    int s = __shfl(x1, k, 8);
                    r[8 + k] = hsb[(size_t)s * 8 + lane];
                }
                int cnt = min(16, end - base);
#pragma unroll
                for (int k = 0; k < 16; ++k) {
                    if (k < cnt) {
                        uint4 u = r[k];
                        a0 += bflo(u.x); a1 += bfhi(u.x);
                        a2 += bflo(u.y); a3 += bfhi(u.y);
                        a4 += bflo(u.z); a5 += bfhi(u.z);
                        a6 += bflo(u.w); a7 += bfhi(u.w);
                    }
                }
            }
            float o0 = fmaxf(a0 * sc + bb0.x, 0.f), o1 = fmaxf(a1 * sc + bb0.y, 0.f);
            float o2 = fmaxf(a2 * sc + bb0.z, 0.f), o3 = fmaxf(a3 * sc + bb0.w, 0.f);
            float o4 = fmaxf(a4 * sc + bb1.x, 0.f), o5 = fmaxf(a5 * sc + bb1.y, 0.f);
            float o6 = fmaxf(a6 * sc + bb1.z, 0.f), o7 = fmaxf(a7 * sc + bb1.w, 0.f);
            p0 = (unsigned)f2bf(o0) | ((unsigned)f2bf(o1) << 16);
            p1 = (unsigned)f2bf(o2) | ((unsigned)f2bf(o3) << 16);
            p2 = (unsigned)f2bf(o4) | ((unsigned)f2bf(o5) << 16);
            p3 = (unsigned)f2bf(o6) | ((unsigned)f2bf(o7) << 16);
        }
        *(uint4*)&Act[local * 72 + lane * 8] = make_uint4(p0, p1, p2, p3);
        if (lane == 0) sdv[local] = sc;
    }
    __syncthreads();

    // phase 2: act1(bucket) @ W2, scale by dinv, emit hs2 (sliced layout)
    const int w    = t >> 6;                   // 8 waves
    const int l    = t & 63;
    const int l15  = l & 15;
    const int quad = l >> 4;

    bf16x8 bf[4][2];
#pragma unroll
    for (int nt = 0; nt < 4; ++nt)
#pragma unroll
        for (int kc = 0; kc < 2; ++kc)
            bf[nt][kc] = *(const bf16x8*)&Wl[(nt * 16 + l15) * 72 + kc * 32 + quad * 8];

#pragma unroll
    for (int mt = 0; mt < 2; ++mt) {
        int m0 = w * 32 + mt * 16;
        bf16x8 af0 = *(const bf16x8*)&Act[(m0 + l15) * 72 + quad * 8];
        bf16x8 af1 = *(const bf16x8*)&Act[(m0 + l15) * 72 + 32 + quad * 8];
#pragma unroll
        for (int nt = 0; nt < 4; ++nt) {
            f32x4 z = {0.f, 0.f, 0.f, 0.f};
            z = __builtin_amdgcn_mfma_f32_16x16x32_bf16(af0, bf[nt][0], z, 0, 0, 0);
            z = __builtin_amdgcn_mfma_f32_16x16x32_bf16(af1, bf[nt][1], z, 0, 0, 0);
#pragma unroll
            for (int r = 0; r < 4; ++r) {
                int row = m0 + quad * 4 + r;
                int node = node0 + row;
                if (node < N)
                    hs2[((size_t)nt * N + node) * 16 + l15] = f2bf(z[r] * sdv[row]);
            }
        }
    }
}

// ---- final aggregate, feature-sliced for XCD-L2 confinement (R1 variant) ----
// slice = blockIdx&3 (== XCD-confined under round-robin: block i -> XCD i%8,
// slice i&3 is constant per XCD); panel 3.2MB < 4MB L2. 4 lanes/node.
__global__ __launch_bounds__(256) void k_agg2(const unsigned short* __restrict__ hs2,
                                              const int* __restrict__ rowptr,
                                              const int* __restrict__ csr,
                                              const float* __restrict__ dinv,
                                              const float* __restrict__ b,
                                              float* __restrict__ out, int N) {
    const int slice = blockIdx.x & 3;
    const int chunk = blockIdx.x >> 2;
    const int t = threadIdx.x;
    const int node = chunk * 64 + (t >> 2);
    const int lane = t & 3;
    if (node >= N) return;
    const int beg = rowptr[node];
    const int end = rowptr[node + 1];
    const unsigned short* hp = hs2 + (size_t)slice * N * 16;

    float a[16];
#pragma unroll
    for (int j = 0; j < 16; ++j) a[j] = 0.f;

    // software-pipelined gather: indices for iter i+1 load while iter i's rows land
    int e = beg + lane;
    int i0 = (e < end) ? csr[e] : -1;
    int i1 = (e + 4 < end) ? csr[e + 4] : -1;
    while (i0 >= 0) {
        int i2 = (e + 8  < end) ? csr[e + 8]  : -1;
        int i3 = (e + 12 < end) ? csr[e + 12] : -1;
        {
            const uint4* p = (const uint4*)(hp + (size_t)i0 * 16);
            uint4 u0 = p[0];
            uint4 u1 = p[1];
            a[0] += bflo(u0.x); a[1] += bfhi(u0.x);
            a[2] += bflo(u0.y); a[3] += bfhi(u0.y);
            a[4] += bflo(u0.z); a[5] += bfhi(u0.z);
            a[6] += bflo(u0.w); a[7] += bfhi(u0.w);
            a[8]  += bflo(u1.x); a[9]  += bfhi(u1.x);
            a[10] += bflo(u1.y); a[11] += bfhi(u1.y);
            a[12] += bflo(u1.z); a[13] += bfhi(u1.z);
            a[14] += bflo(u1.w); a[15] += bfhi(u1.w);
        }
        if (i1 >= 0) {
            const uint4* p = (const uint4*)(hp + (size_t)i1 * 16);
            uint4 u0 = p[0];
            uint4 u1 = p[1];
            a[0] += bflo(u0.x); a[1] += bfhi(u0.x);
            a[2] += bflo(u0.y); a[3] += bfhi(u0.y);
            a[4] += bflo(u0.z); a[5] += bfhi(u0.z);
            a[6] += bflo(u0.w); a[7] += bfhi(u0.w);
            a[8]  += bflo(u1.x); a[9]  += bfhi(u1.x);
            a[10] += bflo(u1.y); a[11] += bfhi(u1.y);
            a[12] += bflo(u1.z); a[13] += bfhi(u1.z);
            a[14] += bflo(u1.w); a[15] += bfhi(u1.w);
        }
        i0 = i2;
        i1 = i3;
        e += 8;
    }

    // reduce-scatter over the 4-lane group: lane l ends with features l*4..l*4+3.
    float h[8];
#pragma unroll
    for (int k = 0; k < 8; ++k) {
        float lo = a[k]     + __shfl_xor(a[k], 2, 4);
        float hi = a[k + 8] + __shfl_xor(a[k + 8], 2, 4);
        h[k] = (lane & 2) ? hi : lo;
    }
    float v[4];
#pragma unroll
    for (int k = 0; k < 4; ++k) {
        float lo = h[k]     + __shfl_xor(h[k], 1, 4);
        float hi = h[k + 4] + __shfl_xor(h[k + 4], 1, 4);
        v[k] = (lane & 1) ? hi : lo;
    }

    const float sc = dinv[node];
    const int j0 = lane * 4;                   // this lane writes features j0..j0+3
    uint2 sv = *(const uint2*)(hp + (size_t)node * 16 + j0);   // self loop (4 bf16)
    float s0 = bflo(sv.x), s1 = bfhi(sv.x), s2 = bflo(sv.y), s3 = bfhi(sv.y);
    float4 bb = *(const float4*)&b[slice * 16 + j0];
    float4 o = make_float4((v[0] + s0) * sc + bb.x,
                           (v[1] + s1) * sc + bb.y,
                           (v[2] + s2) * sc + bb.z,
                           (v[3] + s3) * sc + bb.w);
    *(float4*)&out[(size_t)node * F + slice * 16 + j0] = o;
}

extern "C" void kernel_launch(void* const* d_in, const int* in_sizes, int n_in,
                              void* d_out, int out_size, void* d_ws, size_t ws_size,
                              hipStream_t stream) {
    const float* x  = (const float*)d_in[0];
    const int*   ei = (const int*)d_in[1];
    const float* W1 = (const float*)d_in[2];
    const float* b1 = (const float*)d_in[3];
    const float* W2 = (const float*)d_in[4];
    const float* b2 = (const float*)d_in[5];
    float* out = (float*)d_out;

    const int N = in_sizes[0] / F;
    const int E = in_sizes[1] / 2;
    const int* src = ei;
    const int* dst = ei + E;

    const int NB = (N + 255) >> 8;                       // buckets (391)
    const int chunk = (E + NCH - 1) / NCH;
    const int M  = NB * NCH;
    const int Mp = ((M + 1023) / 1024) * 1024;
    const int nb2 = Mp / 1024;                           // <= 256

    // ws: W1t | W2t | dinv | part2 | rowptr | histM | ebuf | csr | hs1 | hs2
    char* ws = (char*)d_ws;
    size_t a = 0;
    unsigned short* W1t = (unsigned short*)(ws + a); a += (4096 * 2 + 255) & ~(size_t)255;
    unsigned short* W2t = (unsigned short*)(ws + a); a += (4096 * 2 + 255) & ~(size_t)255;
    float* dinv   = (float*)(ws + a); a += ((size_t)N * 4 + 255) & ~(size_t)255;
    int*   part2  = (int*)(ws + a);   a += ((size_t)nb2 * 4 + 255) & ~(size_t)255;
    int*   rowptr = (int*)(ws + a);   a += ((size_t)(N + 1) * 4 + 255) & ~(size_t)255;
    int*   histM  = (int*)(ws + a);   a += ((size_t)Mp * 4 + 255) & ~(size_t)255;
    int*   ebuf   = (int*)(ws + a);   a += ((size_t)E * 4 + 255) & ~(size_t)255;
    int*   csr    = (int*)(ws + a);   a += ((size_t)E * 4 + 255) & ~(size_t)255;
    unsigned short* hs1 = (unsigned short*)(ws + a); a += ((size_t)N * F * 2 + 255) & ~(size_t)255;
    unsigned short* hs2 = (unsigned short*)(ws + a);

    const size_t ldsNB = (size_t)NB * 4;
    const int gGemm = (N + 63) / 64;
    const int gAgg2 = ((N + 63) / 64) * 4;               // 4 slices, 64 nodes/block

    // ---- CSR build (R1 structure; scanp inlined into emit -> 8 launches) ----
    k_histprep<<<NCH + 2, 256, ldsNB, stream>>>(dst, histM, W1, W2, W1t, W2t, E, chunk, NB);
    s_part<<<nb2, 256, 0, stream>>>(histM, part2, M);
    s_emit2<<<nb2, 256, 0, stream>>>(histM, part2, M);
    k_scatter2<<<NCH, 256, ldsNB, stream>>>(src, dst, histM, ebuf, E, chunk, NB);
    k_csr<<<NB, 256, 0, stream>>>(ebuf, histM, rowptr, csr, dinv, N, E, NB);

    // ---- layer 1 GEMM, fused agg1+gemm2, sliced final agg (R1 best-measured) ----
    k_gemm1<<<gGemm, 256, 0, stream>>>(x, W1t, dinv, hs1, N);
    k_aggmm<<<NB, 512, 0, stream>>>(hs1, rowptr, csr, W2t, b1, hs2, N);
    k_agg2<<<gAgg2, 256, 0, stream>>>(hs2, rowptr, csr, dinv, b2, out, N);
}